// Round 2
// baseline (3814.732 us; speedup 1.0000x reference)
//
#include <hip/hip_runtime.h>
#include <hip/hip_bf16.h>

// TorchMD_GN_Ext: N=10000 atoms, E=320000 edges, H=F=128, R=50, L=6.
// R2 final: runtime dtype probe (bf16 vs float32) selecting dual-compiled
// bodies; per-layer weights addressed by ELEMENT offset inside kernels (host
// cannot scale pointers without knowing element size); workspace ~46MB;
// chunked edge-message buffer; index clamps + NaN guard.

#define NATOMS 10000
#define NEDGES 320000
#define HC 128
#define FC 128
#define RBF 50
#define RBFP 52
#define NLAY 6
#define EB 16
#define MAXZ_ 100
#define NCHUNK 4
#define CA (NATOMS / NCHUNK)
#define MAXCE 96000
#define FILT_GRID (MAXCE / EB)

typedef __hip_bfloat16 bf16;

__device__ __forceinline__ float b2f(bf16 v) { return __bfloat162float(v); }
__device__ __forceinline__ bf16  f2b(float v) { return __float2bfloat16(v); }

template<int ISF>
__device__ __forceinline__ float LD(const void* p, size_t i) {
    if (ISF) return ((const float*)p)[i];
    return b2f(((const bf16*)p)[i]);
}

__global__ void probe_k(const void* pos, int nelem, int* flag) {
    int i = blockIdx.x * 256 + threadIdx.x;
    float v = 0.0f;
    if (i < nelem) {
        v = fabsf(b2f(((const bf16*)pos)[i]));
        if (v != v) v = 1e30f;
    }
    atomicMax(flag, __float_as_int(v));
}

__global__ void setflag_k(int* flag) {
    if (threadIdx.x == 0 && blockIdx.x == 0)
        flag[1] = (__int_as_float(flag[0]) > 1.0e4f) ? 1 : 0;
}

__global__ void zero_k(int* p, int n) {
    int i = blockIdx.x * 256 + threadIdx.x;
    if (i < n) p[i] = 0;
}

__device__ __forceinline__ int clampN(int v) {
    return v < 0 ? 0 : (v >= NATOMS ? NATOMS - 1 : v);
}

__global__ void hist_k(const int* __restrict__ dst, int* __restrict__ counts) {
    int e = blockIdx.x * 256 + threadIdx.x;
    if (e < NEDGES) atomicAdd(&counts[clampN(dst[e])], 1);
}

__global__ void scan_k(const int* __restrict__ counts, int* __restrict__ rowptr) {
    __shared__ int lds[1024];
    __shared__ int carry;
    int tid = threadIdx.x;
    if (tid == 0) { carry = 0; rowptr[0] = 0; }
    __syncthreads();
    for (int base = 0; base < NATOMS; base += 1024) {
        int i = base + tid;
        int v = (i < NATOMS) ? counts[i] : 0;
        lds[tid] = v;
        __syncthreads();
        for (int off = 1; off < 1024; off <<= 1) {
            int t = (tid >= off) ? lds[tid - off] : 0;
            __syncthreads();
            lds[tid] += t;
            __syncthreads();
        }
        if (i < NATOMS) rowptr[i + 1] = lds[tid] + carry;
        __syncthreads();
        if (tid == 0) carry += lds[1023];
        __syncthreads();
    }
}

__global__ void copy_k(const int* __restrict__ a, int* __restrict__ b, int n) {
    int i = blockIdx.x * 256 + threadIdx.x;
    if (i < n) b[i] = a[i];
}

__global__ void perm_k(const int* __restrict__ dst, int* __restrict__ cursor,
                       int* __restrict__ perm) {
    int e = blockIdx.x * 256 + threadIdx.x;
    if (e < NEDGES) {
        int p = atomicAdd(&cursor[clampN(dst[e])], 1);
        perm[p] = e;
    }
}

template<int ISF>
__device__ void geom_body(const int* __restrict__ ei, const void* __restrict__ pos,
                          const int* __restrict__ perm,
                          float* __restrict__ C_s, float* __restrict__ Cm_s,
                          float* __restrict__ ed_s, int* __restrict__ src_s) {
    int i = blockIdx.x * 256 + threadIdx.x;
    if (i >= NEDGES) return;
    int e = perm[i];
    int s = clampN(ei[e]);
    int t = clampN(ei[NEDGES + e]);
    float dx = LD<ISF>(pos, (size_t)s * 3 + 0) - LD<ISF>(pos, (size_t)t * 3 + 0);
    float dy = LD<ISF>(pos, (size_t)s * 3 + 1) - LD<ISF>(pos, (size_t)t * 3 + 1);
    float dz = LD<ISF>(pos, (size_t)s * 3 + 2) - LD<ISF>(pos, (size_t)t * 3 + 2);
    float d = sqrtf(dx * dx + dy * dy + dz * dz + 1e-12f);
    if (d != d) d = 1e30f;
    float C = (d < 5.0f) ? 0.5f * (__cosf(d * 0.6283185307f) + 1.0f) : 0.0f;
    C_s[i] = C;
    Cm_s[i] = (s != t) ? C : 0.0f;
    ed_s[i] = __expf(-d);
    src_s[i] = s;
}

__global__ void geom_k(const int* ei, const void* pos, const int* perm, const int* flagp,
                       float* C_s, float* Cm_s, float* ed_s, int* src_s) {
    if (flagp[1]) geom_body<1>(ei, pos, perm, C_s, Cm_s, ed_s, src_s);
    else          geom_body<0>(ei, pos, perm, C_s, Cm_s, ed_s, src_s);
}

template<int ISF>
__device__ void nbr_edge_body(const int* __restrict__ rowptr, int a0, int a1,
                              const float* __restrict__ ed_s, const float* __restrict__ C_s,
                              const float* __restrict__ Cm_s, const int* __restrict__ src_s,
                              const int* __restrict__ z, const void* __restrict__ nbr_emb,
                              const void* __restrict__ Wp, const void* __restrict__ bp,
                              const void* __restrict__ means, const void* __restrict__ betas,
                              bf16* __restrict__ medge) {
    __shared__ float attr[EB][RBFP];
    __shared__ float sm[RBF], sb[RBF];
    int e0 = rowptr[a0], e1 = rowptr[a1];
    int i0 = e0 + blockIdx.x * EB;
    if (i0 >= e1) return;
    int f = threadIdx.x;
    if (f < RBF) { sm[f] = LD<ISF>(means, f); sb[f] = LD<ISF>(betas, f); }
    __syncthreads();
    for (int t = f; t < EB * RBFP; t += 128) {
        int e = t / RBFP, r = t - e * RBFP;
        int i = i0 + e;
        float v = 0.0f;
        if (r < RBF && i < e1) {
            float u = ed_s[i] - sm[r];
            v = C_s[i] * __expf(-sb[r] * u * u);
        }
        attr[e][r] = v;
    }
    __syncthreads();
    float acc[EB];
    float bb = LD<ISF>(bp, f);
    #pragma unroll
    for (int e = 0; e < EB; e++) acc[e] = bb;
    for (int r = 0; r < RBF; r++) {
        float w = LD<ISF>(Wp, (size_t)r * HC + f);
        #pragma unroll
        for (int e = 0; e < EB; e++) acc[e] += attr[e][r] * w;
    }
    #pragma unroll
    for (int e = 0; e < EB; e++) {
        int i = i0 + e;
        if (i < e1) {
            int s = src_s[i];
            int zz = z[s]; zz = zz < 0 ? 0 : (zz >= MAXZ_ ? MAXZ_ - 1 : zz);
            float v = acc[e] * Cm_s[i] * LD<ISF>(nbr_emb, (size_t)zz * HC + f);
            medge[(size_t)(i - e0) * FC + f] = f2b(v);
        }
    }
}

__global__ void nbr_edge_k(const int* rowptr, int a0, int a1,
                           const float* ed_s, const float* C_s, const float* Cm_s,
                           const int* src_s, const int* z, const void* nbr_emb,
                           const void* Wp, const void* bp,
                           const void* means, const void* betas,
                           const int* flagp, bf16* medge) {
    if (flagp[1]) nbr_edge_body<1>(rowptr, a0, a1, ed_s, C_s, Cm_s, src_s, z, nbr_emb, Wp, bp, means, betas, medge);
    else          nbr_edge_body<0>(rowptr, a0, a1, ed_s, C_s, Cm_s, src_s, z, nbr_emb, Wp, bp, means, betas, medge);
}

__global__ void nbr_aggr_k(const int* __restrict__ rowptr, int a0,
                           const bf16* __restrict__ medge, float* __restrict__ msg) {
    int n = a0 + blockIdx.x, f = threadIdx.x;
    int e0 = rowptr[a0];
    float acc = 0.0f;
    int i1 = rowptr[n + 1];
    for (int i = rowptr[n]; i < i1; i++) acc += b2f(medge[(size_t)(i - e0) * FC + f]);
    msg[(size_t)n * HC + f] = acc;
}

template<int ISF>
__device__ void combine_body(const int* __restrict__ z, const void* __restrict__ emb,
                             const float* __restrict__ msg, const void* __restrict__ Wc,
                             const void* __restrict__ bc, float* __restrict__ x) {
    __shared__ float row[2 * HC];
    int n = blockIdx.x, j = threadIdx.x;
    int zz = z[n]; zz = zz < 0 ? 0 : (zz >= MAXZ_ ? MAXZ_ - 1 : zz);
    row[j] = LD<ISF>(emb, (size_t)zz * HC + j);
    row[HC + j] = msg[(size_t)n * HC + j];
    __syncthreads();
    float acc = LD<ISF>(bc, j);
    for (int h = 0; h < 2 * HC; h++) acc += row[h] * LD<ISF>(Wc, (size_t)h * HC + j);
    x[(size_t)n * HC + j] = acc;
}

__global__ void combine_k(const int* z, const void* emb, const float* msg,
                          const void* Wc, const void* bc, const int* flagp, float* x) {
    if (flagp[1]) combine_body<1>(z, emb, msg, Wc, bc, x);
    else          combine_body<0>(z, emb, msg, Wc, bc, x);
}

// layer index passed; element offsets computed in-kernel (host can't scale
// pointers without knowing the element size).
template<int ISF>
__device__ void ygemm_body(const float* __restrict__ x, const void* __restrict__ W,
                           size_t w_off, float* __restrict__ y) {
    __shared__ float row[HC];
    int n = blockIdx.x, f = threadIdx.x;
    row[f] = x[(size_t)n * HC + f];
    __syncthreads();
    float acc = 0.0f;
    for (int h = 0; h < HC; h++) acc += row[h] * LD<ISF>(W, w_off + (size_t)h * FC + f);
    y[(size_t)n * FC + f] = acc;
}

__global__ void ygemm_k(const float* x, const void* W, int l, const int* flagp, float* y) {
    size_t w_off = (size_t)l * HC * FC;
    if (flagp[1]) ygemm_body<1>(x, W, w_off, y);
    else          ygemm_body<0>(x, W, w_off, y);
}

template<int ISF>
__device__ void filt_body(const int* __restrict__ rowptr, int a0, int a1, int l,
                          const float* __restrict__ ed_s, const float* __restrict__ C_s,
                          const int* __restrict__ src_s, const float* __restrict__ y,
                          const void* __restrict__ means, const void* __restrict__ betas,
                          const void* __restrict__ W1, const void* __restrict__ b1,
                          const void* __restrict__ W2, const void* __restrict__ b2v,
                          bf16* __restrict__ medge) {
    __shared__ float attr[EB][RBFP];
    __shared__ float hid[EB][FC];
    __shared__ float sm[RBF], sb[RBF];
    size_t o1 = (size_t)l * RBF * FC, ob1 = (size_t)l * FC;
    size_t o2 = (size_t)l * FC * FC,  ob2 = (size_t)l * FC;
    int e0 = rowptr[a0], e1 = rowptr[a1];
    int i0 = e0 + blockIdx.x * EB;
    if (i0 >= e1) return;
    int f = threadIdx.x;
    if (f < RBF) { sm[f] = LD<ISF>(means, f); sb[f] = LD<ISF>(betas, f); }
    __syncthreads();
    for (int t = f; t < EB * RBFP; t += 128) {
        int e = t / RBFP, r = t - e * RBFP;
        int i = i0 + e;
        float v = 0.0f;
        if (r < RBF && i < e1) {
            float u = ed_s[i] - sm[r];
            v = C_s[i] * __expf(-sb[r] * u * u);
        }
        attr[e][r] = v;
    }
    __syncthreads();
    float acc[EB];
    float bb = LD<ISF>(b1, ob1 + f);
    #pragma unroll
    for (int e = 0; e < EB; e++) acc[e] = bb;
    for (int r = 0; r < RBF; r++) {
        float w = LD<ISF>(W1, o1 + (size_t)r * FC + f);
        #pragma unroll
        for (int e = 0; e < EB; e++) acc[e] += attr[e][r] * w;
    }
    #pragma unroll
    for (int e = 0; e < EB; e++) {
        float v = acc[e];
        hid[e][f] = v / (1.0f + __expf(-v));
    }
    __syncthreads();
    float bb2 = LD<ISF>(b2v, ob2 + f);
    #pragma unroll
    for (int e = 0; e < EB; e++) acc[e] = bb2;
    for (int h = 0; h < FC; h++) {
        float w = LD<ISF>(W2, o2 + (size_t)h * FC + f);
        #pragma unroll
        for (int e = 0; e < EB; e++) acc[e] += hid[e][h] * w;
    }
    #pragma unroll
    for (int e = 0; e < EB; e++) {
        int i = i0 + e;
        if (i < e1) {
            float wf = acc[e] * C_s[i];
            float mv = wf * y[(size_t)src_s[i] * FC + f];
            medge[(size_t)(i - e0) * FC + f] = f2b(mv);
        }
    }
}

__global__ void filt_k(const int* rowptr, int a0, int a1, int l,
                       const float* ed_s, const float* C_s, const int* src_s,
                       const float* y, const void* means, const void* betas,
                       const void* W1, const void* b1, const void* W2, const void* b2v,
                       const int* flagp, bf16* medge) {
    if (flagp[1]) filt_body<1>(rowptr, a0, a1, l, ed_s, C_s, src_s, y, means, betas, W1, b1, W2, b2v, medge);
    else          filt_body<0>(rowptr, a0, a1, l, ed_s, C_s, src_s, y, means, betas, W1, b1, W2, b2v, medge);
}

template<int ISF>
__device__ void aggr_body(const int* __restrict__ rowptr, int a0, int l,
                          const bf16* __restrict__ medge,
                          const void* __restrict__ W2c, const void* __restrict__ b2c,
                          const void* __restrict__ Wl, const void* __restrict__ blin,
                          float* __restrict__ x) {
    __shared__ float mrow[FC];
    __shared__ float yrow[FC];
    size_t oc = (size_t)l * FC * HC, obc = (size_t)l * HC;
    size_t ol = (size_t)l * HC * HC, obl = (size_t)l * HC;
    int n = a0 + blockIdx.x, f = threadIdx.x;
    int e0 = rowptr[a0];
    float acc = 0.0f;
    int i1 = rowptr[n + 1];
    for (int i = rowptr[n]; i < i1; i++) acc += b2f(medge[(size_t)(i - e0) * FC + f]);
    mrow[f] = acc;
    __syncthreads();
    float a2 = LD<ISF>(b2c, obc + f);
    for (int h = 0; h < FC; h++) a2 += mrow[h] * LD<ISF>(W2c, oc + (size_t)h * HC + f);
    float s = a2 / (1.0f + __expf(-a2));
    yrow[f] = s;
    __syncthreads();
    float a3 = LD<ISF>(blin, obl + f);
    for (int h = 0; h < HC; h++) a3 += yrow[h] * LD<ISF>(Wl, ol + (size_t)h * HC + f);
    x[(size_t)n * HC + f] += a3;
}

__global__ void aggr_k(const int* rowptr, int a0, int l, const bf16* medge,
                       const void* W2c, const void* b2c, const void* Wl, const void* blin,
                       const int* flagp, float* x) {
    if (flagp[1]) aggr_body<1>(rowptr, a0, l, medge, W2c, b2c, Wl, blin, x);
    else          aggr_body<0>(rowptr, a0, l, medge, W2c, b2c, Wl, blin, x);
}

__global__ void out_k(const float* __restrict__ x, void* out, const int* flagp) {
    int i = blockIdx.x * 256 + threadIdx.x;
    if (i >= NATOMS * HC) return;
    if (flagp[1]) ((float*)out)[i] = x[i];
    else          ((bf16*)out)[i] = f2b(x[i]);
}

extern "C" void kernel_launch(void* const* d_in, const int* in_sizes, int n_in,
                              void* d_out, int out_size, void* d_ws, size_t ws_size,
                              hipStream_t stream) {
    const int*  z      = (const int*) d_in[0];
    const void* pos    = d_in[1];
    const int*  ei     = (const int*) d_in[3];
    const void* emb    = d_in[4];
    const void* nbremb = d_in[5];
    const void* Wp     = d_in[6];
    const void* bp     = d_in[7];
    const void* Wc     = d_in[8];
    const void* bc     = d_in[9];
    const void* means  = d_in[10];
    const void* betas  = d_in[11];
    const void* W1     = d_in[12];
    const void* b1     = d_in[13];
    const void* W2     = d_in[14];
    const void* b2     = d_in[15];
    const void* cW1    = d_in[16];
    const void* cW2    = d_in[17];
    const void* cb2    = d_in[18];
    const void* lW     = d_in[19];
    const void* lb     = d_in[20];

    char* p = (char*)d_ws;
    auto alloc = [&](size_t bytes) { char* r = p; p += (bytes + 255) / 256 * 256; return r; };
    int*   flag   = (int*)  alloc(256);
    int*   counts = (int*)  alloc((size_t)NATOMS * 4);
    int*   rowptr = (int*)  alloc((size_t)(NATOMS + 1) * 4);
    int*   cursor = (int*)  alloc((size_t)NATOMS * 4);
    int*   perm   = (int*)  alloc((size_t)NEDGES * 4);
    int*   src_s  = (int*)  alloc((size_t)NEDGES * 4);
    float* C_s    = (float*)alloc((size_t)NEDGES * 4);
    float* Cm_s   = (float*)alloc((size_t)NEDGES * 4);
    float* ed_s   = (float*)alloc((size_t)NEDGES * 4);
    float* x      = (float*)alloc((size_t)NATOMS * HC * 4);
    float* msg    = (float*)alloc((size_t)NATOMS * HC * 4);
    float* y      = (float*)alloc((size_t)NATOMS * FC * 4);
    bf16*  medge  = (bf16*) alloc((size_t)MAXCE * FC * 2);   // total ~46 MB

    const int EG = (NEDGES + 255) / 256;
    const int NG = (NATOMS + 255) / 256;

    zero_k<<<1, 64, 0, stream>>>(flag, 2);
    zero_k<<<NG, 256, 0, stream>>>(counts, NATOMS);
    probe_k<<<(NATOMS * 3 + 255) / 256, 256, 0, stream>>>(pos, NATOMS * 3, flag);
    setflag_k<<<1, 64, 0, stream>>>(flag);

    hist_k<<<EG, 256, 0, stream>>>(ei + NEDGES, counts);
    scan_k<<<1, 1024, 0, stream>>>(counts, rowptr);
    copy_k<<<NG, 256, 0, stream>>>(rowptr, cursor, NATOMS);
    perm_k<<<EG, 256, 0, stream>>>(ei + NEDGES, cursor, perm);
    geom_k<<<EG, 256, 0, stream>>>(ei, pos, perm, flag, C_s, Cm_s, ed_s, src_s);

    for (int c = 0; c < NCHUNK; c++) {
        int a0 = c * CA, a1 = a0 + CA;
        nbr_edge_k<<<FILT_GRID, 128, 0, stream>>>(rowptr, a0, a1, ed_s, C_s, Cm_s, src_s,
                                                  z, nbremb, Wp, bp, means, betas, flag, medge);
        nbr_aggr_k<<<CA, 128, 0, stream>>>(rowptr, a0, medge, msg);
    }
    combine_k<<<NATOMS, 128, 0, stream>>>(z, emb, msg, Wc, bc, flag, x);

    for (int l = 0; l < NLAY; l++) {
        ygemm_k<<<NATOMS, 128, 0, stream>>>(x, cW1, l, flag, y);
        for (int c = 0; c < NCHUNK; c++) {
            int a0 = c * CA, a1 = a0 + CA;
            filt_k<<<FILT_GRID, 128, 0, stream>>>(rowptr, a0, a1, l, ed_s, C_s, src_s, y,
                                                  means, betas, W1, b1, W2, b2, flag, medge);
            aggr_k<<<CA, 128, 0, stream>>>(rowptr, a0, l, medge, cW2, cb2, lW, lb, flag, x);
        }
    }
    out_k<<<(NATOMS * HC + 255) / 256, 256, 0, stream>>>(x, d_out, flag);
}